// Round 5
// baseline (441.198 us; speedup 1.0000x reference)
//
#include <hip/hip_runtime.h>

// SpectralPooling: x (4,64,64,64,32) f32 -> out (4,32,32,32,32) f32.
// DCT64->trunc24->pad32->iDCT32 per axis == one 32x64 matrix A (all axes).
// Round 5: 3 dispatches, no k0 (A computed inline in f32 per block),
// cross-tile double-buffered global_load_lds prefetch with counted vmcnt,
// (4o x 4c)-per-lane float4 compute (2x ds_read_b128 + 16 fmac per k).
//
// P1 contract w: x[(b,d,h)][64w][32c]        -> y1[(b,d,h)][32r][32c]
// P2 contract h: y1[b,d][64h][jt*32]         -> y2[b][q][d][32r][32c]
// P3 contract d: y2[b,q][64d][jt*32] (+T)    -> out[b][r][q][32d'][32c]
// out layout check: reference = transpose(z,(0,3,2,1,4)) = out[b][r][q][d'][c]. OK
// ws: y1 64 MiB | y2 32 MiB

template<int PASS> struct Cfg;
template<> struct Cfg<1> { static constexpr int KS = 32;   static constexpr int NT = 8; static constexpr long OS = 32;    };
template<> struct Cfg<2> { static constexpr int KS = 1024; static constexpr int NT = 4; static constexpr long OS = 65536; };
template<> struct Cfg<3> { static constexpr int KS = 1024; static constexpr int NT = 2; static constexpr long OS = 32;    };

template<int PASS>
__device__ __forceinline__ void tile_bases(long tau, long& ib, long& ob) {
    if constexpr (PASS == 1) {
        ib = tau * 2048;                       // x: [16384 t][64 w][32 c]
        ob = tau * 1024;                       // y1: [16384 t][32 r][32 c]
    } else if constexpr (PASS == 2) {
        long bd = tau >> 5, jt = tau & 31;     // bd = b*64+d
        long b = bd >> 6, d = bd & 63;
        ib = bd * 65536 + jt * 32;             // y1 rows: h stride 1024
        ob = b * 2097152 + d * 1024 + jt * 32; // y2: [b][q][d][32r][32c], q stride 65536
    } else {
        long bq = tau >> 5, jt = tau & 31;     // bq = b*32+q, jt = r
        long b = bq >> 5, q = bq & 31;
        ib = (b * 32 + q) * 65536 + jt * 32;   // y2 rows: d stride 1024
        ob = ((b * 32 + jt) * 32 + q) * 1024;  // out: contiguous [32 d'][32 c]
    }
}

template<int PASS>
__global__ __launch_bounds__(256) void sp_pass(const float* __restrict__ X,
                                               float* __restrict__ Y) {
    constexpr int  KS = Cfg<PASS>::KS;
    constexpr long OS = Cfg<PASS>::OS;
    constexpr int  NT = Cfg<PASS>::NT;

    __shared__ float As[2048];           // As[k*32+o] = A[o][k]
    __shared__ float tiles[4][2][2048];  // [wave][dbuf][64 k x 32]

    int t = threadIdx.x;
    // Inline A (f32): A[o][k] = sum_p s32(p)s64(p) cos(pi(o+.5)p/32) cos(pi(k+.5)p/64)
    for (int i = t; i < 2048; i += 256) {
        int k = i >> 5, o = i & 31;
        float fo = (o + 0.5f) * (3.14159265358979f / 32.0f);
        float fk = (k + 0.5f) * (3.14159265358979f / 64.0f);
        float s = 0.02209708691f;                      // p=0: sqrt(1/32)*sqrt(1/64)
        for (int p = 1; p < 24; ++p)
            s += 0.04419417382f * cosf(fo * p) * cosf(fk * p); // sqrt(2/32)*sqrt(2/64)
        As[i] = s;
    }
    __syncthreads();

    int wave = t >> 6, lane = t & 63;
    int o4 = lane >> 3, c4 = lane & 7;
    long wg = (long)blockIdx.x * 4 + wave;   // 0..2047

    float* b0 = &tiles[wave][0][0];
    float* b1 = &tiles[wave][1][0];

    const float* Xl = X + (long)(lane >> 3) * KS + (lane & 7) * 4;
    auto issue = [&](float* buf, long ib) {
        const float* g = Xl + ib;
#pragma unroll
        for (int i = 0; i < 8; ++i)
            __builtin_amdgcn_global_load_lds(
                (const __attribute__((address_space(1))) void*)(g + (long)i * (8 * KS)),
                (__attribute__((address_space(3))) void*)(buf + i * 256), 16, 0, 0);
    };

    long ib, ob;
    tile_bases<PASS>(wg * NT + 0, ib, ob); issue(b0, ib);
    tile_bases<PASS>(wg * NT + 1, ib, ob); issue(b1, ib);

    const float4* ab = (const float4*)As;

#pragma unroll 1
    for (int i = 0; i < NT; ++i) {
        // Counted waits (in-order vmcnt retire): guarantee tile i's 8 loads done.
        // after L_i: [L_{i+1}: 8 if exists] + [S_{i-1}: 4 if i>0]
        if (i == 0)           asm volatile("s_waitcnt vmcnt(8)"  ::: "memory");
        else if (i == NT - 1) asm volatile("s_waitcnt vmcnt(4)"  ::: "memory");
        else                  asm volatile("s_waitcnt vmcnt(12)" ::: "memory");
        __builtin_amdgcn_sched_barrier(0);

        const float4* tb = (const float4*)((i & 1) ? b1 : b0);

        float4 a0 = make_float4(0.f, 0.f, 0.f, 0.f);
        float4 a1 = a0, a2 = a0, a3 = a0;
#pragma unroll
        for (int k = 0; k < 64; ++k) {
            float4 xv = tb[k * 8 + c4];   // ds_read_b128, 8 distinct addrs, broadcast
            float4 av = ab[k * 8 + o4];   // ds_read_b128, 8 distinct addrs, broadcast
            a0.x += av.x * xv.x; a0.y += av.x * xv.y; a0.z += av.x * xv.z; a0.w += av.x * xv.w;
            a1.x += av.y * xv.x; a1.y += av.y * xv.y; a1.z += av.y * xv.z; a1.w += av.y * xv.w;
            a2.x += av.z * xv.x; a2.y += av.z * xv.y; a2.z += av.z * xv.z; a2.w += av.z * xv.w;
            a3.x += av.w * xv.x; a3.y += av.w * xv.y; a3.z += av.w * xv.z; a3.w += av.w * xv.w;
        }

        // All ds_reads of this buffer retired before overwriting it with tile i+2.
        asm volatile("s_waitcnt lgkmcnt(0)" ::: "memory");
        __builtin_amdgcn_sched_barrier(0);
        if (i + 2 < NT) {
            long ibn, obn;
            tile_bases<PASS>(wg * NT + i + 2, ibn, obn);
            issue((i & 1) ? b1 : b0, ibn);
        }

        long ibc, obc;
        tile_bases<PASS>(wg * NT + i, ibc, obc);
        float* dst = Y + obc + (long)(o4 * 4) * OS + c4 * 4;
        *(float4*)(dst)          = a0;
        *(float4*)(dst + OS)     = a1;
        *(float4*)(dst + 2 * OS) = a2;
        *(float4*)(dst + 3 * OS) = a3;
    }
}

extern "C" void kernel_launch(void* const* d_in, const int* in_sizes, int n_in,
                              void* d_out, int out_size, void* d_ws, size_t ws_size,
                              hipStream_t stream) {
    const float* x = (const float*)d_in[0];   // 33,554,432 f32
    float* out = (float*)d_out;               // 4,194,304 f32

    float* y1 = (float*)d_ws;                 // 16,777,216 f32 (64 MiB)
    float* y2 = y1 + 16777216;                // 8,388,608 f32 (32 MiB)

    // 2048 waves each (512 blocks x 4 waves), tiles/wave: 8 / 4 / 2
    sp_pass<1><<<512, 256, 0, stream>>>(x,  y1);
    sp_pass<2><<<512, 256, 0, stream>>>(y1, y2);
    sp_pass<3><<<512, 256, 0, stream>>>(y2, out);
}

// Round 7
// 297.631 us; speedup vs baseline: 1.4824x; 1.4824x over previous
//
#include <hip/hip_runtime.h>

// SpectralPooling: x (4,64,64,64,32) f32 -> out (4,32,32,32,32) f32.
// DCT64->trunc24->pad32->iDCT32 per axis == one 32x64 matrix A (all axes);
// the three axis contractions commute -> contract W, then H, then D.
// Round 7: TWO plain dispatches (no cooperative launch).
//  K_A (block=(b,d), 512 thr): fuses W and H contractions. x rows x[b,d,h,:,:]
//    stream through a 4-deep LDS ring (1 global_load_lds 16B/thread/row,
//    s_waitcnt vmcnt(2), one barrier per h). Thread (r,c2) W-contracts row h
//    into a float2 IN REGISTERS, then immediately H-accumulates into 32
//    per-thread float2 accumulators (y1 intermediate never hits memory).
//    Writes y1[b][q][d][r][c] (32 MiB).
//  K_B: = round-4's proven pass-3: per-wave [64d x 128B] tiles of y1,
//    contract d -> out[b][r][q][d'][c] (the reference transpose(0,3,2,1,4)).
// A(32x64) built per block: f64 Chebyshev recurrence, 2 cos() seeds/entry.
// ws: y1 32 MiB only.

__device__ __forceinline__ void fill_As(float* As) {
    // As[k*32+o] = A[o][k]; A[o][k] = sum_{p<24} s(p) cos(pi(o+.5)p/32) cos(pi(k+.5)p/64)
    for (int i = threadIdx.x; i < 2048; i += blockDim.x) {
        int k = i >> 5, o = i & 31;
        double to = cos((o + 0.5) * (3.14159265358979323846 / 32.0));
        double tk = cos((k + 0.5) * (3.14159265358979323846 / 64.0));
        double co0 = 1.0, co1 = to, ck0 = 1.0, ck1 = tk;
        double w2o = 2.0 * to, w2k = 2.0 * tk;
        double s = 0.022097086912079608;            // p=0: sqrt(1/32)*sqrt(1/64)
        #pragma unroll 1
        for (int p = 1; p < 24; ++p) {
            s += 0.044194173824159216 * co1 * ck1;  // sqrt(2/32)*sqrt(2/64)
            double con = w2o * co1 - co0; co0 = co1; co1 = con;
            double ckn = w2k * ck1 - ck0; ck0 = ck1; ck1 = ckn;
        }
        As[i] = (float)s;
    }
}

__global__ __launch_bounds__(512, 2) void sp_fuse_wh(const float* __restrict__ X,
                                                     float* __restrict__ Y1) {
    __shared__ float As[2048];        // 8 KB
    __shared__ float xrow[4][2048];   // 32 KB: 4-deep ring of [64 w][32 c] rows

    int t = threadIdx.x;
    int b = blockIdx.x >> 6, d = blockIdx.x & 63;
    const float* xbase = X + ((long)(b * 64 + d) << 17);   // slab of 64 h-rows

    auto stage = [&](int h) {   // whole block stages one 8 KB row, 16 B/thread
        const float* src = xbase + h * 2048 + t * 4;
        float* dstb = &xrow[h & 3][(t >> 6) << 8];         // wave-uniform base
        __builtin_amdgcn_global_load_lds(
            (const __attribute__((address_space(1))) void*)src,
            (__attribute__((address_space(3))) void*)dstb, 16, 0, 0);
    };

    stage(0); stage(1); stage(2);     // HBM latency overlaps fill_As below
    fill_As(As);
    __syncthreads();                  // As ready

    int r = t >> 4;                   // 0..31 (W-output row this thread owns)
    int c2 = t & 15;                  // float2 channel column

    float ar[64];                     // A[r][:] hoisted to VGPRs
#pragma unroll
    for (int w = 0; w < 64; ++w) ar[w] = As[w * 32 + r];

    float2 qa[32];                    // per-thread H accumulators (all 32 q)
#pragma unroll
    for (int q = 0; q < 32; ++q) qa[q] = make_float2(0.f, 0.f);

#pragma unroll 1
    for (int h = 0; h < 64; ++h) {
        if (h < 61) asm volatile("s_waitcnt vmcnt(2)" ::: "memory");
        else        asm volatile("s_waitcnt vmcnt(0)" ::: "memory");
        __syncthreads();              // row h landed everywhere; ring slot free
        if (h + 3 < 64) stage(h + 3);

        // W-contract row h: v = sum_w A[r][w] * x[h][w][c2 pair]
        const float* xr = &xrow[h & 3][0];
        float2 v = make_float2(0.f, 0.f);
#pragma unroll
        for (int w = 0; w < 64; ++w) {
            float2 xv = *(const float2*)&xr[w * 32 + c2 * 2];
            v.x += ar[w] * xv.x; v.y += ar[w] * xv.y;
        }

        // H-accumulate: qa[q] += A[q][h] * v   (A[:,h] = As[h*32..], bcast b128)
        const float4* ah = (const float4*)&As[h * 32];
#pragma unroll
        for (int qg = 0; qg < 8; ++qg) {
            float4 a4 = ah[qg];
            qa[qg * 4 + 0].x += a4.x * v.x; qa[qg * 4 + 0].y += a4.x * v.y;
            qa[qg * 4 + 1].x += a4.y * v.x; qa[qg * 4 + 1].y += a4.y * v.y;
            qa[qg * 4 + 2].x += a4.z * v.x; qa[qg * 4 + 2].y += a4.z * v.y;
            qa[qg * 4 + 3].x += a4.w * v.x; qa[qg * 4 + 3].y += a4.w * v.y;
        }
    }

    // y1[b][q][d][r][c]: per q a contiguous 4 KB block-wide store
#pragma unroll
    for (int q = 0; q < 32; ++q) {
        float* dst = Y1 + ((long)((b * 32 + q) * 64 + d) << 10) + r * 32 + c2 * 2;
        *(float2*)dst = qa[q];
    }
}

// K_B = round-4's pass 3 (proven): contract d, write transposed output.
__global__ __launch_bounds__(256) void sp_pass_d(const float* __restrict__ Y1,
                                                 float* __restrict__ Out) {
    __shared__ float As[2048];        // As[k*32+o] = A[o][k]
    __shared__ float tiles[4][2048];  // per-wave [64 d][32 f] tile

    fill_As(As);
    __syncthreads();

    int t = threadIdx.x;
    int wave = t >> 6, lane = t & 63;
    long tile = (long)blockIdx.x * 4 + wave;          // (b,q,r) flat, 4096 total
    long b = tile >> 10;
    int q = ((int)tile >> 5) & 31, r = (int)tile & 31;

    long ib = (b * 32 + q) * 65536 + r * 32;          // y1 rows: d stride 1024
    float* ltile = &tiles[wave][0];
    const float* gsrc = Y1 + ib + (long)(lane >> 3) * 1024 + (lane & 7) * 4;
#pragma unroll
    for (int i = 0; i < 8; ++i)
        __builtin_amdgcn_global_load_lds(
            (const __attribute__((address_space(1))) void*)(gsrc + (long)i * 8192),
            (__attribute__((address_space(3))) void*)(ltile + i * 256), 16, 0, 0);
    asm volatile("s_waitcnt vmcnt(0)" ::: "memory");
    __builtin_amdgcn_sched_barrier(0);

    int j2 = lane & 15, og = lane >> 4;
    const float2* xs  = (const float2*)ltile + j2;    // + k*16
    const float4* as4 = (const float4*)As + og * 2;   // + k*8

    float2 acc[8];
#pragma unroll
    for (int i = 0; i < 8; ++i) acc[i] = make_float2(0.f, 0.f);

#pragma unroll
    for (int k = 0; k < 64; ++k) {
        float2 xv = xs[k * 16];
        float4 a0 = as4[k * 8];
        float4 a1 = as4[k * 8 + 1];
        acc[0].x += a0.x * xv.x; acc[0].y += a0.x * xv.y;
        acc[1].x += a0.y * xv.x; acc[1].y += a0.y * xv.y;
        acc[2].x += a0.z * xv.x; acc[2].y += a0.z * xv.y;
        acc[3].x += a0.w * xv.x; acc[3].y += a0.w * xv.y;
        acc[4].x += a1.x * xv.x; acc[4].y += a1.x * xv.y;
        acc[5].x += a1.y * xv.x; acc[5].y += a1.y * xv.y;
        acc[6].x += a1.z * xv.x; acc[6].y += a1.z * xv.y;
        acc[7].x += a1.w * xv.x; acc[7].y += a1.w * xv.y;
    }

    // out[b][r][q][d'][c], contiguous [32 d'][32 c] per tile
    long ob = ((b * 32 + r) * 32 + q) * 1024;
    float2* dst = (float2*)(Out + ob) + j2;
#pragma unroll
    for (int i = 0; i < 8; ++i) {
        int o = og * 8 + i;
        dst[o * 16] = acc[i];
    }
}

extern "C" void kernel_launch(void* const* d_in, const int* in_sizes, int n_in,
                              void* d_out, int out_size, void* d_ws, size_t ws_size,
                              hipStream_t stream) {
    const float* x = (const float*)d_in[0];   // 33,554,432 f32
    float* out = (float*)d_out;               // 4,194,304 f32
    float* y1 = (float*)d_ws;                 // 8,388,608 f32 (32 MiB)

    // K_A: 256 blocks = (b,d); fused W+H contraction -> y1[b][q][d][r][c]
    sp_fuse_wh<<<256, 512, 0, stream>>>(x, y1);

    // K_B: 4096 per-wave tiles / 4 per block; contract d + transposed write
    sp_pass_d<<<1024, 256, 0, stream>>>(y1, out);
}